// Round 5
// baseline (2729.110 us; speedup 1.0000x reference)
//
#include <hip/hip_runtime.h>
#include <hip/hip_bf16.h>

// Problem constants (B=4, L=1024, D=1024, H=16, Dh=64, MAX_LEN=150)
#define BB 4
#define LL 1024
#define DD 1024
#define HH 16
#define DH 64
#define NPOS 301      // 2*MAX_LEN+1
#define MAXL 150
#define NEG_INF -1e30f

// ---------------------------------------------------------------------------
// GEMM: C = A @ W^T + bias.  A[M,K] f32 row-major, W[N,K] f32 row-major.
// MODE 1: qkv permuted write -> out[((b*H+h)*L + l)*64 + dh] ([B,H,L,Dh])
// MODE 2: C f32 [M,N] plain row-major  (final projection -- d_out IS f32:
//         rounds 1-4's bit-identical absmax was the bf16-written/f32-read
//         decimation signature)
// Tiles: 64x64 output, BK=16, 256 threads, 4x4 micro-tile per thread.
// ---------------------------------------------------------------------------
template <int MODE>
__global__ __launch_bounds__(256) void gemm_tn(
    const float* __restrict__ A, const float* __restrict__ W,
    const float* __restrict__ bias, float* __restrict__ Cout,
    int M, int N, int K)
{
    __shared__ float As[16][64 + 4];
    __shared__ float Ws[16][64 + 4];
    const int tid = threadIdx.x;
    const int m0 = blockIdx.y * 64;
    const int n0 = blockIdx.x * 64;
    const int tx = tid & 15, ty = tid >> 4;
    const int lr = tid >> 2;           // 0..63 tile row to load
    const int lk = (tid & 3) << 2;     // 0,4,8,12 k-offset to load

    float acc[4][4] = {};

    for (int k0 = 0; k0 < K; k0 += 16) {
        float4 av = *reinterpret_cast<const float4*>(A + (size_t)(m0 + lr) * K + (k0 + lk));
        As[lk + 0][lr] = av.x; As[lk + 1][lr] = av.y;
        As[lk + 2][lr] = av.z; As[lk + 3][lr] = av.w;
        float4 wv = *reinterpret_cast<const float4*>(W + (size_t)(n0 + lr) * K + (k0 + lk));
        Ws[lk + 0][lr] = wv.x; Ws[lk + 1][lr] = wv.y;
        Ws[lk + 2][lr] = wv.z; Ws[lk + 3][lr] = wv.w;
        __syncthreads();
#pragma unroll
        for (int kk = 0; kk < 16; ++kk) {
            float4 a4 = *reinterpret_cast<const float4*>(&As[kk][ty << 2]);
            float4 b4 = *reinterpret_cast<const float4*>(&Ws[kk][tx << 2]);
            float a[4] = {a4.x, a4.y, a4.z, a4.w};
            float b[4] = {b4.x, b4.y, b4.z, b4.w};
#pragma unroll
            for (int i = 0; i < 4; ++i)
#pragma unroll
                for (int j = 0; j < 4; ++j)
                    acc[i][j] = fmaf(a[i], b[j], acc[i][j]);
        }
        __syncthreads();
    }

#pragma unroll
    for (int i = 0; i < 4; ++i) {
        const int r = m0 + (ty << 2) + i;
#pragma unroll
        for (int j = 0; j < 4; ++j) {
            const int c = n0 + (tx << 2) + j;
            float val = acc[i][j] + (bias ? bias[c] : 0.f);
            if (MODE == 1) {
                const int b = r >> 10, l = r & 1023, hh = c >> 6, dh = c & 63;
                Cout[(((size_t)(b * HH + hh)) * LL + l) * DH + dh] = val;
            } else {
                Cout[(size_t)r * N + c] = val;
            }
        }
    }
}

// ---------------------------------------------------------------------------
// Flash-style attention, f32.  One block = one (b,h) and TQ=32 query rows.
// S = (q.k + q.pos_emb[idx(k-q)]) / 8, masked -> online softmax -> P@V.
// Rp computed inline from pos_emb (77 KB, L2-resident).
// Mask read as int32 words; !=0 is correct for int32 and f32 storage alike
// (established rounds 1->2: byte-storage branch changed nothing).
// ---------------------------------------------------------------------------
#define TQ 32
#define TK 64

__global__ __launch_bounds__(256) void attn_fwd(
    const float* __restrict__ qb, const float* __restrict__ kb,
    const float* __restrict__ vb, const float* __restrict__ pe,
    const int* __restrict__ mask, float* __restrict__ outb)
{
    const int bh = blockIdx.y;          // 0..63
    const int b = bh >> 4, h = bh & 15;
    const int q0 = blockIdx.x * TQ;
    const int tid = threadIdx.x;

    __shared__ float qs[TQ][DH + 1];
    __shared__ float ks[TK][DH + 1];
    __shared__ float vs[TK][DH];
    __shared__ float S[TQ][TK + 1];
    __shared__ float rowm[TQ], rowl[TQ], rowal[TQ];

    const size_t qbase = ((size_t)bh * LL + q0) * DH;
    for (int i = tid; i < TQ * DH / 4; i += 256) {
        const int r = i >> 4, c = (i & 15) << 2;
        float4 v4 = *reinterpret_cast<const float4*>(qb + qbase + r * DH + c);
        qs[r][c] = v4.x; qs[r][c + 1] = v4.y; qs[r][c + 2] = v4.z; qs[r][c + 3] = v4.w;
    }
    if (tid < TQ) { rowm[tid] = NEG_INF; rowl[tid] = 0.f; }

    float Oacc[8] = {};
    const int qi = tid >> 3;            // owned q row (0..31)
    const int kj0 = (tid & 7) << 3;     // owned 8 k-columns / 8 dh-columns
    __syncthreads();

    for (int k0 = 0; k0 < LL; k0 += TK) {
        // ---- stage K and V tiles ----
        const size_t kvbase = ((size_t)bh * LL + k0) * DH;
        for (int i = tid; i < TK * DH / 4; i += 256) {
            const int r = i >> 4, c = (i & 15) << 2;
            float4 k4 = *reinterpret_cast<const float4*>(kb + kvbase + r * DH + c);
            ks[r][c] = k4.x; ks[r][c + 1] = k4.y; ks[r][c + 2] = k4.z; ks[r][c + 3] = k4.w;
            float4 v4 = *reinterpret_cast<const float4*>(vb + kvbase + r * DH + c);
            vs[r][c] = v4.x; vs[r][c + 1] = v4.y; vs[r][c + 2] = v4.z; vs[r][c + 3] = v4.w;
        }
        __syncthreads();

        // ---- S = (q.k + q.R) / 8, masked ----
        float dot[8] = {};
        for (int d = 0; d < DH; ++d) {
            const float qv = qs[qi][d];
#pragma unroll
            for (int j = 0; j < 8; ++j)
                dot[j] = fmaf(qv, ks[kj0 + j][d], dot[j]);
        }
        {
            const int gq = q0 + qi;
            const size_t mrow = ((size_t)b * LL + gq) * LL;
#pragma unroll
            for (int j = 0; j < 8; ++j) {
                const int gk = k0 + kj0 + j;
                int rel = gk - gq;
                rel = rel < -MAXL ? -MAXL : (rel > MAXL ? MAXL : rel);
                int idx = rel + MAXL - 1;
                if (idx < 0) idx += NPOS;      // torch negative-index wraparound
                const float* per = pe + (size_t)idx * DH;
                float rp = 0.f;
                for (int d = 0; d < DH; d += 4) {
                    float4 p4 = *reinterpret_cast<const float4*>(per + d);
                    rp = fmaf(qs[qi][d + 0], p4.x, rp);
                    rp = fmaf(qs[qi][d + 1], p4.y, rp);
                    rp = fmaf(qs[qi][d + 2], p4.z, rp);
                    rp = fmaf(qs[qi][d + 3], p4.w, rp);
                }
                float sv = (dot[j] + rp) * 0.125f;
                if (mask[mrow + gk] != 0) sv = NEG_INF;
                S[qi][kj0 + j] = sv;
            }
        }
        __syncthreads();

        // ---- online softmax update (one thread per row) ----
        if (tid < TQ) {
            float tmax = NEG_INF;
            for (int j = 0; j < TK; ++j) tmax = fmaxf(tmax, S[tid][j]);
            const float nm = fmaxf(rowm[tid], tmax);
            const float al = expf(rowm[tid] - nm);
            float ls = 0.f;
            for (int j = 0; j < TK; ++j) {
                const float p = expf(S[tid][j] - nm);
                S[tid][j] = p;
                ls += p;
            }
            rowl[tid] = rowl[tid] * al + ls;
            rowm[tid] = nm;
            rowal[tid] = al;
        }
        __syncthreads();

        // ---- O = al*O + P @ V ----
        {
            const float al = rowal[qi];
#pragma unroll
            for (int t = 0; t < 8; ++t) Oacc[t] *= al;
            for (int kk = 0; kk < TK; ++kk) {
                const float p = S[qi][kk];
                const float4 va = *reinterpret_cast<const float4*>(&vs[kk][kj0]);
                const float4 vc = *reinterpret_cast<const float4*>(&vs[kk][kj0 + 4]);
                Oacc[0] = fmaf(p, va.x, Oacc[0]); Oacc[1] = fmaf(p, va.y, Oacc[1]);
                Oacc[2] = fmaf(p, va.z, Oacc[2]); Oacc[3] = fmaf(p, va.w, Oacc[3]);
                Oacc[4] = fmaf(p, vc.x, Oacc[4]); Oacc[5] = fmaf(p, vc.y, Oacc[5]);
                Oacc[6] = fmaf(p, vc.z, Oacc[6]); Oacc[7] = fmaf(p, vc.w, Oacc[7]);
            }
        }
        __syncthreads();
    }

    const float inv = 1.f / rowl[qi];
    const size_t obase = ((size_t)b * LL + (q0 + qi)) * DD + h * DH + kj0;
#pragma unroll
    for (int t = 0; t < 8; ++t) outb[obase + t] = Oacc[t] * inv;
}

// ---------------------------------------------------------------------------
// Inputs (dict order): 0 Q, 1 K, 2 V, 3 mask, 4 Wq, 5 bq, 6 Wk, 7 bk,
// 8 Wv, 9 bv, 10 Wo, 11 bo, 12 pos_emb.  Output: [B, L, D] float32.
// Workspace (f32): qbuf/kbuf/vbuf [B,H,L,Dh] + attn [B,L,D] = 64 MB.
// ---------------------------------------------------------------------------
extern "C" void kernel_launch(void* const* d_in, const int* in_sizes, int n_in,
                              void* d_out, int out_size, void* d_ws, size_t ws_size,
                              hipStream_t stream)
{
    const float *Q, *K, *V, *Wq, *bq, *Wk, *bk, *Wv, *bv, *Wo, *bo, *pe;
    const int* mask;
    if (in_sizes[3] == 1024 * 1024) {            // alphabetical ordering (defensive)
        K  = (const float*)d_in[0];
        Q  = (const float*)d_in[1];
        V  = (const float*)d_in[2];
        Wk = (const float*)d_in[3];
        Wo = (const float*)d_in[4];
        Wq = (const float*)d_in[5];
        Wv = (const float*)d_in[6];
        bk = (const float*)d_in[7];
        bo = (const float*)d_in[8];
        bq = (const float*)d_in[9];
        bv = (const float*)d_in[10];
        mask = (const int*)d_in[11];
        pe = (const float*)d_in[12];
    } else {                                     // documented dict ordering
        Q  = (const float*)d_in[0];
        K  = (const float*)d_in[1];
        V  = (const float*)d_in[2];
        mask = (const int*)d_in[3];
        Wq = (const float*)d_in[4];
        bq = (const float*)d_in[5];
        Wk = (const float*)d_in[6];
        bk = (const float*)d_in[7];
        Wv = (const float*)d_in[8];
        bv = (const float*)d_in[9];
        Wo = (const float*)d_in[10];
        bo = (const float*)d_in[11];
        pe = (const float*)d_in[12];
    }
    float* out = (float*)d_out;                  // f32 output buffer

    float* ws = (float*)d_ws;
    const size_t NQ = (size_t)BB * HH * LL * DH;       // 4,194,304
    float* qbuf = ws;
    float* kbuf = qbuf + NQ;
    float* vbuf = kbuf + NQ;
    float* attn = vbuf + NQ;                           // [B, L, D]

    const dim3 blk(256);
    const int M = BB * LL;                             // 4096

    gemm_tn<1><<<dim3(DD / 64, M / 64), blk, 0, stream>>>(Q, Wq, bq, qbuf, M, DD, DD);
    gemm_tn<1><<<dim3(DD / 64, M / 64), blk, 0, stream>>>(K, Wk, bk, kbuf, M, DD, DD);
    gemm_tn<1><<<dim3(DD / 64, M / 64), blk, 0, stream>>>(V, Wv, bv, vbuf, M, DD, DD);
    attn_fwd<<<dim3(LL / TQ, BB * HH), blk, 0, stream>>>(qbuf, kbuf, vbuf, pe, mask, attn);
    gemm_tn<2><<<dim3(DD / 64, M / 64), blk, 0, stream>>>(attn, Wo, bo, out, M, DD, DD);
}

// Round 6
// 745.357 us; speedup vs baseline: 3.6615x; 3.6615x over previous
//
#include <hip/hip_runtime.h>
#include <hip/hip_bf16.h>

// Problem constants (B=4, L=1024, D=1024, H=16, Dh=64, MAX_LEN=150)
#define BB 4
#define LL 1024
#define DD 1024
#define HH 16
#define DH 64
#define NPOS 301      // 2*MAX_LEN+1
#define MAXL 150
#define NEG_INF -1e30f

typedef __attribute__((ext_vector_type(4))) float f32x4;
typedef __attribute__((ext_vector_type(8))) short short8;

__device__ inline unsigned short f2b(float x) {
    __hip_bfloat16 h = __float2bfloat16(x);
    return *reinterpret_cast<unsigned short*>(&h);
}
__device__ inline unsigned pack2(float a, float b) {
    return (unsigned)f2b(a) | ((unsigned)f2b(b) << 16);
}

// ---------------------------------------------------------------------------
// GEMM: C = A @ W^T + bias.  A[M,K] f32 row-major, W[N,K] f32 row-major.
// MODE 0: C f32 [M,N] plain row-major (GN=true adds N-guards; used for Qpos
//         table N=301 and for the final projection N=1024)
// MODE 1: f32 permuted write -> out[((b*H+h)*L+l)*64+dh]   ([B,H,L,Dh])
// MODE 4: bf16 permuted write (same layout, ushort)
// ---------------------------------------------------------------------------
template <int MODE, bool GN>
__global__ __launch_bounds__(256) void gemm_tn(
    const float* __restrict__ A, const float* __restrict__ W,
    const float* __restrict__ bias, void* __restrict__ Cout,
    int M, int N, int K)
{
    __shared__ float As[16][64 + 4];
    __shared__ float Ws[16][64 + 4];
    const int tid = threadIdx.x;
    const int m0 = blockIdx.y * 64;
    const int n0 = blockIdx.x * 64;
    const int tx = tid & 15, ty = tid >> 4;
    const int lr = tid >> 2;           // 0..63 tile row to load
    const int lk = (tid & 3) << 2;     // 0,4,8,12 k-offset to load

    float acc[4][4] = {};

    for (int k0 = 0; k0 < K; k0 += 16) {
        float4 av = *reinterpret_cast<const float4*>(A + (size_t)(m0 + lr) * K + (k0 + lk));
        As[lk + 0][lr] = av.x; As[lk + 1][lr] = av.y;
        As[lk + 2][lr] = av.z; As[lk + 3][lr] = av.w;
        float4 wv = make_float4(0.f, 0.f, 0.f, 0.f);
        if (!GN || (n0 + lr) < N)
            wv = *reinterpret_cast<const float4*>(W + (size_t)(n0 + lr) * K + (k0 + lk));
        Ws[lk + 0][lr] = wv.x; Ws[lk + 1][lr] = wv.y;
        Ws[lk + 2][lr] = wv.z; Ws[lk + 3][lr] = wv.w;
        __syncthreads();
#pragma unroll
        for (int kk = 0; kk < 16; ++kk) {
            float4 a4 = *reinterpret_cast<const float4*>(&As[kk][ty << 2]);
            float4 b4 = *reinterpret_cast<const float4*>(&Ws[kk][tx << 2]);
            float a[4] = {a4.x, a4.y, a4.z, a4.w};
            float b[4] = {b4.x, b4.y, b4.z, b4.w};
#pragma unroll
            for (int i = 0; i < 4; ++i)
#pragma unroll
                for (int j = 0; j < 4; ++j)
                    acc[i][j] = fmaf(a[i], b[j], acc[i][j]);
        }
        __syncthreads();
    }

#pragma unroll
    for (int i = 0; i < 4; ++i) {
        const int r = m0 + (ty << 2) + i;
#pragma unroll
        for (int j = 0; j < 4; ++j) {
            const int c = n0 + (tx << 2) + j;
            if (GN && c >= N) continue;
            float val = acc[i][j] + (bias ? bias[c] : 0.f);
            if (MODE == 0) {
                ((float*)Cout)[(size_t)r * N + c] = val;
            } else if (MODE == 1) {
                const int b = r >> 10, l = r & 1023, hh = c >> 6, dh = c & 63;
                ((float*)Cout)[(((size_t)(b * HH + hh)) * LL + l) * DH + dh] = val;
            } else {
                const int b = r >> 10, l = r & 1023, hh = c >> 6, dh = c & 63;
                ((unsigned short*)Cout)[(((size_t)(b * HH + hh)) * LL + l) * DH + dh] = f2b(val);
            }
        }
    }
}

// f32 -> bf16 elementwise (4 elems/thread)
__global__ __launch_bounds__(256) void conv_bf16(const float* __restrict__ in,
                                                 unsigned short* __restrict__ out)
{
    const size_t i = ((size_t)blockIdx.x * 256 + threadIdx.x) * 4;
    float4 v = *reinterpret_cast<const float4*>(in + i);
    ushort4 u;
    u.x = f2b(v.x); u.y = f2b(v.y); u.z = f2b(v.z); u.w = f2b(v.w);
    *reinterpret_cast<ushort4*>(out + i) = u;
}

// bf16 [bh][k][dh] -> vT [bh][dh][k]  (block = one (bh, dh) row of vT)
__global__ __launch_bounds__(256) void transpose_v(const unsigned short* __restrict__ vbf,
                                                   unsigned short* __restrict__ vT)
{
    const int dh = blockIdx.x;          // 0..63
    const int bh = blockIdx.y;          // 0..63
    const int k0 = threadIdx.x * 4;
    const size_t ib = (size_t)bh * LL * DH;
    ushort4 o;
    o.x = vbf[ib + (size_t)(k0 + 0) * DH + dh];
    o.y = vbf[ib + (size_t)(k0 + 1) * DH + dh];
    o.z = vbf[ib + (size_t)(k0 + 2) * DH + dh];
    o.w = vbf[ib + (size_t)(k0 + 3) * DH + dh];
    *reinterpret_cast<ushort4*>(vT + ib + (size_t)dh * LL + k0) = o;
}

// ---------------------------------------------------------------------------
// MFMA attention. Block = (bh, 64 q-rows); 4 waves x 16 q-rows each.
// Swapped QK^T: S^T[k][q] = mfma(A=K-frag, B=Q-frag) so each lane owns 16 k's
// of ONE q-row (C layout: row=k=(g*4+r)+16m, col=q=lane&15) -> in-register
// online softmax (2 shfl_xor per reduction). P packed bf16 into a private
// per-wave LDS scratch (XOR-swizzled rows, G4), re-read as PV B-frags.
// PV: O^T[dh][q] = mfma(A=V^T-frag, B=P-frag). K/V/mask/qpos read from
// global (panels are L2-resident; bh = fast grid dim for XCD locality).
// No __syncthreads anywhere in the main loop.
// ---------------------------------------------------------------------------
__global__ __launch_bounds__(256) void attn_mfma(
    const unsigned short* __restrict__ qbf,   // [bh][l][dh] bf16
    const unsigned short* __restrict__ kbf,   // [bh][l][dh] bf16
    const unsigned short* __restrict__ vT,    // [bh][dh][l] bf16
    const float* __restrict__ qpos,           // [bh*L][301] f32
    const int* __restrict__ mask,             // [b][q][k] int32/f32-nonzero
    float* __restrict__ outb)                 // [b][l][D] f32
{
    const int bh = blockIdx.x;                // fast dim -> XCD panel locality
    const int qblk = blockIdx.y;
    const int b = bh >> 4, h = bh & 15;
    const int tid = threadIdx.x;
    const int w = tid >> 6;
    const int lane = tid & 63;
    const int g = lane >> 4;                  // 0..3
    const int qc = lane & 15;                 // 0..15
    const int gq = qblk * 64 + w * 16 + qc;   // this lane's global q row

    __shared__ alignas(16) unsigned char Plds[4 * 2048];
    unsigned char* myP = Plds + w * 2048 + qc * 128;
    const int swz = (qc & 7) << 4;

    // Q B-frags (held across all k-tiles): lane holds Q[q=qc][g*8 .. +7] (+32)
    const unsigned short* qrow = qbf + ((size_t)bh * LL + gq) * DH;
    const short8 qf0 = *reinterpret_cast<const short8*>(qrow + g * 8);
    const short8 qf1 = *reinterpret_cast<const short8*>(qrow + g * 8 + 32);

    const unsigned short* kb0 = kbf + (size_t)bh * LL * DH;
    const unsigned short* vb0 = vT + (size_t)bh * DH * LL;
    const int* mrp = mask + ((size_t)b * LL + gq) * LL;
    const float* qpr = qpos + ((size_t)bh * LL + gq) * NPOS;

    float mrun = -3.0e38f, lrun = 0.f;
    f32x4 o[4];
#pragma unroll
    for (int m = 0; m < 4; ++m) o[m] = (f32x4){0.f, 0.f, 0.f, 0.f};

    for (int kt = 0; kt < LL; kt += 64) {
        // ---- S^T = K . Q^T ----
        f32x4 s[4];
#pragma unroll
        for (int m = 0; m < 4; ++m) s[m] = (f32x4){0.f, 0.f, 0.f, 0.f};
#pragma unroll
        for (int m = 0; m < 4; ++m) {
            const unsigned short* krow = kb0 + (size_t)(kt + m * 16 + qc) * DH + g * 8;
            short8 a0 = *reinterpret_cast<const short8*>(krow);
            short8 a1 = *reinterpret_cast<const short8*>(krow + 32);
            s[m] = __builtin_amdgcn_mfma_f32_16x16x32_bf16(a0, qf0, s[m], 0, 0, 0);
            s[m] = __builtin_amdgcn_mfma_f32_16x16x32_bf16(a1, qf1, s[m], 0, 0, 0);
        }

        // ---- scores: + qpos gather, *1/8, mask ----
        float sv[4][4];
        float tmax = -3.0e38f;
#pragma unroll
        for (int m = 0; m < 4; ++m) {
            const int kb = kt + m * 16 + g * 4;
            const int4 mv = *reinterpret_cast<const int4*>(mrp + kb);
#pragma unroll
            for (int r = 0; r < 4; ++r) {
                const int k = kb + r;
                int rel = k - gq;
                rel = rel < -MAXL ? -MAXL : (rel > MAXL ? MAXL : rel);
                int idx = rel + MAXL - 1;
                if (idx < 0) idx += NPOS;      // torch negative-index wraparound
                float x = (s[m][r] + qpr[idx]) * 0.125f;
                const int mk = (r == 0 ? mv.x : r == 1 ? mv.y : r == 2 ? mv.z : mv.w);
                x = mk ? NEG_INF : x;
                sv[m][r] = x;
                tmax = fmaxf(tmax, x);
            }
        }

        // ---- online softmax (in-register; q-row spans lanes {l, l^16, l^32, l^48}) ----
        tmax = fmaxf(tmax, __shfl_xor(tmax, 16));
        tmax = fmaxf(tmax, __shfl_xor(tmax, 32));
        const float nm = fmaxf(mrun, tmax);
        const float al = __expf(mrun - nm);
        mrun = nm;
        float ls = 0.f;
#pragma unroll
        for (int m = 0; m < 4; ++m)
#pragma unroll
            for (int r = 0; r < 4; ++r) {
                const float p = __expf(sv[m][r] - nm);
                sv[m][r] = p;
                ls += p;
            }
        ls += __shfl_xor(ls, 16);
        ls += __shfl_xor(ls, 32);
        lrun = lrun * al + ls;
#pragma unroll
        for (int m = 0; m < 4; ++m) o[m] *= al;

        // ---- P -> bf16 -> private LDS (swizzled), re-read as B-frags ----
#pragma unroll
        for (int m = 0; m < 4; ++m) {
            *reinterpret_cast<unsigned*>(myP + ((32 * m + 8 * g) ^ swz)) = pack2(sv[m][0], sv[m][1]);
            *reinterpret_cast<unsigned*>(myP + ((32 * m + 8 * g + 4) ^ swz)) = pack2(sv[m][2], sv[m][3]);
        }
        const short8 pf0 = *reinterpret_cast<const short8*>(myP + ((16 * g) ^ swz));
        const short8 pf1 = *reinterpret_cast<const short8*>(myP + ((64 + 16 * g) ^ swz));

        // ---- O^T += V^T . P^T ----
#pragma unroll
        for (int m = 0; m < 4; ++m) {
            const unsigned short* vrow = vb0 + (size_t)(m * 16 + qc) * LL + kt + g * 8;
            short8 va0 = *reinterpret_cast<const short8*>(vrow);
            short8 va1 = *reinterpret_cast<const short8*>(vrow + 32);
            o[m] = __builtin_amdgcn_mfma_f32_16x16x32_bf16(va0, pf0, o[m], 0, 0, 0);
            o[m] = __builtin_amdgcn_mfma_f32_16x16x32_bf16(va1, pf1, o[m], 0, 0, 0);
        }
    }

    const float inv = 1.f / lrun;
    float* orow = outb + ((size_t)b * LL + gq) * DD + h * DH;
#pragma unroll
    for (int m = 0; m < 4; ++m)
#pragma unroll
        for (int r = 0; r < 4; ++r)
            orow[m * 16 + g * 4 + r] = o[m][r] * inv;
}

// ---------------------------------------------------------------------------
// Inputs (dict order): 0 Q, 1 K, 2 V, 3 mask, 4 Wq, 5 bq, 6 Wk, 7 bk,
// 8 Wv, 9 bv, 10 Wo, 11 bo, 12 pos_emb.  Output: [B, L, D] float32.
// Workspace: qbuf f32 + attn f32 + qpos f32 + {qbf,kbf,vbf,vT} bf16
//          = 146,014,208 B (byte-identical footprint to round 1 -> fits).
// ---------------------------------------------------------------------------
extern "C" void kernel_launch(void* const* d_in, const int* in_sizes, int n_in,
                              void* d_out, int out_size, void* d_ws, size_t ws_size,
                              hipStream_t stream)
{
    const float* Q  = (const float*)d_in[0];
    const float* K  = (const float*)d_in[1];
    const float* V  = (const float*)d_in[2];
    const int* mask = (const int*)d_in[3];
    const float* Wq = (const float*)d_in[4];
    const float* bq = (const float*)d_in[5];
    const float* Wk = (const float*)d_in[6];
    const float* bk = (const float*)d_in[7];
    const float* Wv = (const float*)d_in[8];
    const float* bv = (const float*)d_in[9];
    const float* Wo = (const float*)d_in[10];
    const float* bo = (const float*)d_in[11];
    const float* pe = (const float*)d_in[12];
    float* out = (float*)d_out;

    float* ws = (float*)d_ws;
    const size_t NQ = (size_t)BB * HH * LL * DH;       // 4,194,304
    float* qbuf = ws;                                  // f32 [bh][l][dh]
    float* attn = qbuf + NQ;                           // f32 [B,L,D]
    float* qpos = attn + NQ;                           // f32 [bh*L][301]
    unsigned short* qbf = (unsigned short*)(qpos + (size_t)BB * HH * LL * NPOS);
    unsigned short* kbf = qbf + NQ;
    unsigned short* vbf = kbf + NQ;
    unsigned short* vT  = vbf + NQ;

    const dim3 blk(256);
    const int M = BB * LL;                             // 4096

    gemm_tn<1, false><<<dim3(DD / 64, M / 64), blk, 0, stream>>>(Q, Wq, bq, qbuf, M, DD, DD);
    gemm_tn<4, false><<<dim3(DD / 64, M / 64), blk, 0, stream>>>(K, Wk, bk, kbf, M, DD, DD);
    gemm_tn<4, false><<<dim3(DD / 64, M / 64), blk, 0, stream>>>(V, Wv, bv, vbf, M, DD, DD);
    gemm_tn<0, true><<<dim3((NPOS + 63) / 64, (BB * HH * LL) / 64), blk, 0, stream>>>(
        qbuf, pe, nullptr, qpos, BB * HH * LL, NPOS, DH);
    conv_bf16<<<dim3(NQ / 1024), blk, 0, stream>>>(qbuf, qbf);
    transpose_v<<<dim3(DH, BB * HH), blk, 0, stream>>>(vbf, vT);
    attn_mfma<<<dim3(BB * HH, LL / 64), blk, 0, stream>>>(qbf, kbf, vT, qpos, mask, attn);
    gemm_tn<0, false><<<dim3(DD / 64, M / 64), blk, 0, stream>>>(attn, Wo, bo, out, M, DD, DD);
}

// Round 7
// 357.403 us; speedup vs baseline: 7.6359x; 2.0855x over previous
//
#include <hip/hip_runtime.h>
#include <hip/hip_bf16.h>

// Problem constants (B=4, L=1024, D=1024, H=16, Dh=64, MAX_LEN=150)
#define BB 4
#define LL 1024
#define DD 1024
#define HH 16
#define DH 64
#define NPOS 301      // 2*MAX_LEN+1
#define MAXL 150
#define NEG_INF -1e30f

typedef __attribute__((ext_vector_type(4))) float f32x4;
typedef __attribute__((ext_vector_type(8))) short short8;

__device__ inline unsigned short f2b(float x) {
    __hip_bfloat16 h = __float2bfloat16(x);
    return *reinterpret_cast<unsigned short*>(&h);
}
__device__ inline unsigned pack2(float a, float b) {
    return (unsigned)f2b(a) | ((unsigned)f2b(b) << 16);
}

// ---------------------------------------------------------------------------
// f32 -> bf16 conversion, 8 elems/thread, n % 8 == 0 (guarded tail blocks)
// ---------------------------------------------------------------------------
__global__ __launch_bounds__(256) void conv_b16(const float* __restrict__ in,
                                                unsigned short* __restrict__ out, int n)
{
    const size_t i = ((size_t)blockIdx.x * 256 + threadIdx.x) * 8;
    if (i >= (size_t)n) return;
    float4 a = *reinterpret_cast<const float4*>(in + i);
    float4 b = *reinterpret_cast<const float4*>(in + i + 4);
    ushort4 u0 = {f2b(a.x), f2b(a.y), f2b(a.z), f2b(a.w)};
    ushort4 u1 = {f2b(b.x), f2b(b.y), f2b(b.z), f2b(b.w)};
    *reinterpret_cast<ushort4*>(out + i) = u0;
    *reinterpret_cast<ushort4*>(out + i + 4) = u1;
}

// ---------------------------------------------------------------------------
// bf16 MFMA GEMM: C = (A @ W^T + bias) * oscale.
// A bf16 [M][K] rm, W bf16 [N][K] rm, bias f32[N] or null.
// Tile 128(M) x 64(N), BK=32, 256 thr = 4 waves (2x2), wave owns 64x32.
// LDS rows padded to 40 elems (80 B): frag ds_read_b128 hits 8 distinct bank
// groups per 8 lanes (2-way max aliasing = free, m136). Reg-staged (no
// global_load_lds: padding is incompatible with its linear-dest rule, m173).
// Fragment mapping = the one VALIDATED by round 6's attention kernel:
//   A-frag: lane holds A[row=l&15][k=(l>>4)*8..+7]
//   B-frag: lane holds W[col=l&15][k=(l>>4)*8..+7]
//   C:      col = l&15, row = (l>>4)*4 + reg        [m89]
// EPI 0: f32 [M][N] (GN guards col<N)          (qpos table, final output)
// EPI 1: bf16 permuted [bh][l][dh]             (q/k projections)
// EPI 2: bf16 transposed [bh][dh][l]           (v projection -> V^T direct)
// ---------------------------------------------------------------------------
template <int EPI, bool GN>
__global__ __launch_bounds__(256) void gemm_mfma(
    const unsigned short* __restrict__ A, const unsigned short* __restrict__ W,
    const float* __restrict__ bias, void* __restrict__ Cout,
    int M, int N, int K, float oscale)
{
    __shared__ alignas(16) unsigned short As[128 * 40];
    __shared__ alignas(16) unsigned short Bs[64 * 40];
    const int tid = threadIdx.x;
    const int w = tid >> 6, lane = tid & 63;
    const int wr = w >> 1, wc = w & 1;
    const int g = lane >> 4, fr = lane & 15;
    const int m0 = blockIdx.y * 128;
    const int n0 = blockIdx.x * 64;

    f32x4 acc[4][2];
#pragma unroll
    for (int i = 0; i < 4; ++i)
#pragma unroll
        for (int j = 0; j < 2; ++j) acc[i][j] = (f32x4){0.f, 0.f, 0.f, 0.f};

    const int arow0 = tid >> 2, agg = tid & 3;      // A chunks tid, tid+256
    for (int k0 = 0; k0 < K; k0 += 32) {
        {
            short8 v0 = *reinterpret_cast<const short8*>(
                A + (size_t)(m0 + arow0) * K + k0 + agg * 8);
            short8 v1 = *reinterpret_cast<const short8*>(
                A + (size_t)(m0 + arow0 + 64) * K + k0 + agg * 8);
            int nr = n0 + arow0;
            if (GN && nr >= N) nr = N - 1;
            short8 bv = *reinterpret_cast<const short8*>(
                W + (size_t)nr * K + k0 + agg * 8);
            *reinterpret_cast<short8*>(&As[arow0 * 40 + agg * 8]) = v0;
            *reinterpret_cast<short8*>(&As[(arow0 + 64) * 40 + agg * 8]) = v1;
            *reinterpret_cast<short8*>(&Bs[arow0 * 40 + agg * 8]) = bv;
        }
        __syncthreads();
        short8 af[4], bf[2];
#pragma unroll
        for (int i = 0; i < 4; ++i)
            af[i] = *reinterpret_cast<const short8*>(
                &As[(wr * 64 + i * 16 + fr) * 40 + g * 8]);
#pragma unroll
        for (int j = 0; j < 2; ++j)
            bf[j] = *reinterpret_cast<const short8*>(
                &Bs[(wc * 32 + j * 16 + fr) * 40 + g * 8]);
#pragma unroll
        for (int i = 0; i < 4; ++i)
#pragma unroll
            for (int j = 0; j < 2; ++j)
                acc[i][j] = __builtin_amdgcn_mfma_f32_16x16x32_bf16(
                    af[i], bf[j], acc[i][j], 0, 0, 0);
        __syncthreads();
    }

#pragma unroll
    for (int i = 0; i < 4; ++i) {
#pragma unroll
        for (int j = 0; j < 2; ++j) {
#pragma unroll
            for (int r = 0; r < 4; ++r) {
                const int row = m0 + wr * 64 + i * 16 + g * 4 + r;
                const int col = n0 + wc * 32 + j * 16 + fr;
                if (GN && col >= N) continue;
                const float val = (acc[i][j][r] + (bias ? bias[col] : 0.f)) * oscale;
                if (EPI == 0) {
                    ((float*)Cout)[(size_t)row * N + col] = val;
                } else if (EPI == 1) {
                    const int b = row >> 10, l = row & 1023, hh = col >> 6, dh = col & 63;
                    ((unsigned short*)Cout)[(((size_t)(b * HH + hh)) * LL + l) * DH + dh] = f2b(val);
                } else {
                    const int b = row >> 10, l = row & 1023, hh = col >> 6, dh = col & 63;
                    ((unsigned short*)Cout)[(((size_t)(b * HH + hh)) * DH + dh) * LL + l] = f2b(val);
                }
            }
        }
    }
}

// ---------------------------------------------------------------------------
// MFMA attention (validated round 6). Block = (bh, 64 q-rows); 4 waves x 16 q.
// q pre-scaled by 1/8 at projection (exact pow2) -> score = s + qpos, no mul.
// Writes bf16 [b][l][D] so the final projection is MFMA too.
// ---------------------------------------------------------------------------
__global__ __launch_bounds__(256) void attn_mfma(
    const unsigned short* __restrict__ qbf,   // [bh][l][dh] bf16 (scaled 1/8)
    const unsigned short* __restrict__ kbf,   // [bh][l][dh] bf16
    const unsigned short* __restrict__ vT,    // [bh][dh][l] bf16
    const float* __restrict__ qpos,           // [bh*L][301] f32 (scaled 1/8)
    const int* __restrict__ mask,             // [b][q][k] int32/f32-nonzero
    unsigned short* __restrict__ outb)        // [b][l][D] bf16
{
    const int bh = blockIdx.x;                // fast dim -> XCD panel locality
    const int qblk = blockIdx.y;
    const int b = bh >> 4, h = bh & 15;
    const int tid = threadIdx.x;
    const int w = tid >> 6;
    const int lane = tid & 63;
    const int g = lane >> 4;
    const int qc = lane & 15;
    const int gq = qblk * 64 + w * 16 + qc;

    __shared__ alignas(16) unsigned char Plds[4 * 2048];
    unsigned char* myP = Plds + w * 2048 + qc * 128;
    const int swz = (qc & 7) << 4;

    const unsigned short* qrow = qbf + ((size_t)bh * LL + gq) * DH;
    const short8 qf0 = *reinterpret_cast<const short8*>(qrow + g * 8);
    const short8 qf1 = *reinterpret_cast<const short8*>(qrow + g * 8 + 32);

    const unsigned short* kb0 = kbf + (size_t)bh * LL * DH;
    const unsigned short* vb0 = vT + (size_t)bh * DH * LL;
    const int* mrp = mask + ((size_t)b * LL + gq) * LL;
    const float* qpr = qpos + ((size_t)bh * LL + gq) * NPOS;

    float mrun = -3.0e38f, lrun = 0.f;
    f32x4 o[4];
#pragma unroll
    for (int m = 0; m < 4; ++m) o[m] = (f32x4){0.f, 0.f, 0.f, 0.f};

    for (int kt = 0; kt < LL; kt += 64) {
        f32x4 s[4];
#pragma unroll
        for (int m = 0; m < 4; ++m) s[m] = (f32x4){0.f, 0.f, 0.f, 0.f};
#pragma unroll
        for (int m = 0; m < 4; ++m) {
            const unsigned short* krow = kb0 + (size_t)(kt + m * 16 + qc) * DH + g * 8;
            short8 a0 = *reinterpret_cast<const short8*>(krow);
            short8 a1 = *reinterpret_cast<const short8*>(krow + 32);
            s[m] = __builtin_amdgcn_mfma_f32_16x16x32_bf16(a0, qf0, s[m], 0, 0, 0);
            s[m] = __builtin_amdgcn_mfma_f32_16x16x32_bf16(a1, qf1, s[m], 0, 0, 0);
        }

        float sv[4][4];
        float tmax = -3.0e38f;
#pragma unroll
        for (int m = 0; m < 4; ++m) {
            const int kb = kt + m * 16 + g * 4;
            const int4 mv = *reinterpret_cast<const int4*>(mrp + kb);
#pragma unroll
            for (int r = 0; r < 4; ++r) {
                const int k = kb + r;
                int rel = k - gq;
                rel = rel < -MAXL ? -MAXL : (rel > MAXL ? MAXL : rel);
                int idx = rel + MAXL - 1;
                if (idx < 0) idx += NPOS;      // torch negative-index wraparound
                float x = s[m][r] + qpr[idx];  // both pre-scaled by 1/8
                const int mk = (r == 0 ? mv.x : r == 1 ? mv.y : r == 2 ? mv.z : mv.w);
                x = mk ? NEG_INF : x;
                sv[m][r] = x;
                tmax = fmaxf(tmax, x);
            }
        }

        tmax = fmaxf(tmax, __shfl_xor(tmax, 16));
        tmax = fmaxf(tmax, __shfl_xor(tmax, 32));
        const float nm = fmaxf(mrun, tmax);
        const float al = __expf(mrun - nm);
        mrun = nm;
        float ls = 0.f;
#pragma unroll
        for (int m = 0; m < 4; ++m)
#pragma unroll
            for (int r = 0; r < 4; ++r) {
                const float p = __expf(sv[m][r] - nm);
                sv[m][r] = p;
                ls += p;
            }
        ls += __shfl_xor(ls, 16);
        ls += __shfl_xor(ls, 32);
        lrun = lrun * al + ls;
#pragma unroll
        for (int m = 0; m < 4; ++m) o[m] *= al;

#pragma unroll
        for (int m = 0; m < 4; ++m) {
            *reinterpret_cast<unsigned*>(myP + ((32 * m + 8 * g) ^ swz)) = pack2(sv[m][0], sv[m][1]);
            *reinterpret_cast<unsigned*>(myP + ((32 * m + 8 * g + 4) ^ swz)) = pack2(sv[m][2], sv[m][3]);
        }
        const short8 pf0 = *reinterpret_cast<const short8*>(myP + ((16 * g) ^ swz));
        const short8 pf1 = *reinterpret_cast<const short8*>(myP + ((64 + 16 * g) ^ swz));

#pragma unroll
        for (int m = 0; m < 4; ++m) {
            const unsigned short* vrow = vb0 + (size_t)(m * 16 + qc) * LL + kt + g * 8;
            short8 va0 = *reinterpret_cast<const short8*>(vrow);
            short8 va1 = *reinterpret_cast<const short8*>(vrow + 32);
            o[m] = __builtin_amdgcn_mfma_f32_16x16x32_bf16(va0, pf0, o[m], 0, 0, 0);
            o[m] = __builtin_amdgcn_mfma_f32_16x16x32_bf16(va1, pf1, o[m], 0, 0, 0);
        }
    }

    const float inv = 1.f / lrun;
    unsigned short* orow = outb + ((size_t)b * LL + gq) * DD + h * DH;
#pragma unroll
    for (int m = 0; m < 4; ++m)
#pragma unroll
        for (int r = 0; r < 4; ++r)
            orow[m * 16 + g * 4 + r] = f2b(o[m][r] * inv);
}

// ---------------------------------------------------------------------------
// Inputs (dict order): 0 Q, 1 K, 2 V, 3 mask, 4 Wq, 5 bq, 6 Wk, 7 bk,
// 8 Wv, 9 bv, 10 Wo, 11 bo, 12 pos_emb.  Output: [B, L, D] float32.
// Workspace (ushort units unless noted):
//   qbf kbf vT Qc Kc Vc : 6 x 4M          (24 MB..)
//   Wqb Wkb Wvb Wob     : 4 x 1M
//   qpos f32 [65536][301]                  (78.9 MB)
//   attnb bf16 [B,L,D]  (pebf ALIASED at its start: pe's last read -- the
//   qpos GEMM -- precedes attn's first write, stream-ordered)
// Total 146,014,208 B == round-1 footprint (known to fit).
// ---------------------------------------------------------------------------
extern "C" void kernel_launch(void* const* d_in, const int* in_sizes, int n_in,
                              void* d_out, int out_size, void* d_ws, size_t ws_size,
                              hipStream_t stream)
{
    const float* Q  = (const float*)d_in[0];
    const float* K  = (const float*)d_in[1];
    const float* V  = (const float*)d_in[2];
    const int* mask = (const int*)d_in[3];
    const float* Wq = (const float*)d_in[4];
    const float* bq = (const float*)d_in[5];
    const float* Wk = (const float*)d_in[6];
    const float* bk = (const float*)d_in[7];
    const float* Wv = (const float*)d_in[8];
    const float* bv = (const float*)d_in[9];
    const float* Wo = (const float*)d_in[10];
    const float* bo = (const float*)d_in[11];
    const float* pe = (const float*)d_in[12];
    float* out = (float*)d_out;

    unsigned short* ws = (unsigned short*)d_ws;
    const size_t NQ = (size_t)BB * HH * LL * DH;       // 4,194,304
    const size_t NW = (size_t)DD * DD;                 // 1,048,576
    unsigned short* qbf = ws;
    unsigned short* kbf = qbf + NQ;
    unsigned short* vT  = kbf + NQ;
    unsigned short* Qc  = vT + NQ;
    unsigned short* Kc  = Qc + NQ;
    unsigned short* Vc  = Kc + NQ;
    unsigned short* Wqb = Vc + NQ;
    unsigned short* Wkb = Wqb + NW;
    unsigned short* Wvb = Wkb + NW;
    unsigned short* Wob = Wvb + NW;
    float* qpos = (float*)(Wob + NW);                  // byte 56M, 16B aligned
    unsigned short* attnb = (unsigned short*)(qpos + (size_t)BB * HH * LL * NPOS);
    unsigned short* peb = attnb;                       // aliased (disjoint lifetime)

    const dim3 blk(256);
    const int M = BB * LL;                             // 4096
    const int NE = (int)NQ, NWE = (int)NW;

    conv_b16<<<dim3(NE / 2048), blk, 0, stream>>>(Q, Qc, NE);
    conv_b16<<<dim3(NE / 2048), blk, 0, stream>>>(K, Kc, NE);
    conv_b16<<<dim3(NE / 2048), blk, 0, stream>>>(V, Vc, NE);
    conv_b16<<<dim3(NWE / 2048), blk, 0, stream>>>(Wq, Wqb, NWE);
    conv_b16<<<dim3(NWE / 2048), blk, 0, stream>>>(Wk, Wkb, NWE);
    conv_b16<<<dim3(NWE / 2048), blk, 0, stream>>>(Wv, Wvb, NWE);
    conv_b16<<<dim3(NWE / 2048), blk, 0, stream>>>(Wo, Wob, NWE);
    conv_b16<<<dim3(10), blk, 0, stream>>>(pe, peb, NPOS * DH);

    gemm_mfma<1, false><<<dim3(16, 32), blk, 0, stream>>>(Qc, Wqb, bq, qbf, M, DD, DD, 0.125f);
    gemm_mfma<1, false><<<dim3(16, 32), blk, 0, stream>>>(Kc, Wkb, bk, kbf, M, DD, DD, 1.0f);
    gemm_mfma<2, false><<<dim3(16, 32), blk, 0, stream>>>(Vc, Wvb, bv, vT, M, DD, DD, 1.0f);
    gemm_mfma<0, true><<<dim3(5, 512), blk, 0, stream>>>(
        qbf, peb, nullptr, qpos, BB * HH * LL, NPOS, DH, 1.0f);
    attn_mfma<<<dim3(BB * HH, LL / 64), blk, 0, stream>>>(qbf, kbf, vT, qpos, mask, attnb);
    gemm_mfma<0, false><<<dim3(16, 32), blk, 0, stream>>>(attnb, Wob, bo, out, M, DD, DD, 1.0f);
}